// Round 2
// baseline (148.945 us; speedup 1.0000x reference)
//
#include <hip/hip_runtime.h>
#include <hip/hip_bf16.h>

#define T_DIM 8192
#define H_DIM 2048
#define D_DIM 1024
#define PAD_R 32          // zero lead rows of xb = scan warm-up window
#define KT    16          // K tiles of BK=64

typedef __bf16 bf16x8 __attribute__((ext_vector_type(8)));
typedef float floatx4 __attribute__((ext_vector_type(4)));
typedef unsigned short u16;

__device__ __forceinline__ u16 f2bf(float f) {
    __hip_bfloat16 b = __float2bfloat16(f);
    return *reinterpret_cast<u16*>(&b);
}
__device__ __forceinline__ float bf2f(u16 v) {
    return __uint_as_float((unsigned)v << 16);
}

#define GLDS(g, l) \
    __builtin_amdgcn_global_load_lds((const __attribute__((address_space(1))) void*)(g), \
                                     (__attribute__((address_space(3))) void*)(l), 16, 0, 0)

// ---------------------------------------------------------------------------
// fp32 -> bf16 convert: xb gets 32 leading ZERO rows (scan warm-up), then x;
// bb = B. ~63MB traffic -> ~10us at BW.
// ---------------------------------------------------------------------------
__global__ __launch_bounds__(256) void conv_kernel(const float* __restrict__ x,
                                                   const float* __restrict__ Bm,
                                                   u16* __restrict__ xb,
                                                   u16* __restrict__ bb) {
    const int nPad4 = PAD_R * D_DIM / 4;
    const int nX4   = (T_DIM + PAD_R) * D_DIM / 4;
    const int nB4   = H_DIM * D_DIM / 4;
    int i = blockIdx.x * 256 + threadIdx.x;
    if (i < nX4) {
        ushort4 o;
        if (i < nPad4) {
            o.x = o.y = o.z = o.w = 0;
        } else {
            const float4 v = reinterpret_cast<const float4*>(x)[i - nPad4];
            o.x = f2bf(v.x); o.y = f2bf(v.y); o.z = f2bf(v.z); o.w = f2bf(v.w);
        }
        reinterpret_cast<ushort4*>(xb)[i] = o;
    } else {
        i -= nX4;
        if (i >= nB4) return;
        const float4 v = reinterpret_cast<const float4*>(Bm)[i];
        ushort4 o;
        o.x = f2bf(v.x); o.y = f2bf(v.y); o.z = f2bf(v.z); o.w = f2bf(v.w);
        reinterpret_cast<ushort4*>(bb)[i] = o;
    }
}

// ---------------------------------------------------------------------------
// Fused 288x256 8-phase GEMM + scan (T1+T2+T3+T4+T5 + warm-up recompute).
// 512 thr = 8 waves (2M x 4N), per-wave 144x64 (acc[9][4]), BK=64.
// A tile = 288 rows (32 warm + 256 out). Staging per K-tile: A = 4 full GLDS
// + 1 half (tid<256, wave-uniform); B = 4 GLDS. Granule-XOR swizzle
// (col ^= (row&7)*8) on both stage-source and ds_read -> 0 conflicts.
// LDS: A dbuf 2x36KB + B dbuf 2x32KB = 136KB, reused as u-tile [288][256]
// bf16 (147456B) for the in-block scan epilogue.
// Window j (4 phases, 1 K-tile): P1 ds A(mh0:5)+B(nh0), stage A(j+1)->other;
// P2 ds B(nh1); P3 ds A(mh1:4), stage B(j+2) half0 -> current B buf (old B
// reads done at P2); P4 stage B(j+2) half1, counted vmcnt(4) (in-order
// retirement => A(j+1)+older landed; B(j+2)'s 4 loads stay in flight).
// Epilogue: acc -> LDS (kseg-XOR col swizzle, conflict-free both sides),
// then 512 thr = 2 t-halves x 256 cols run (32 warm + 128 out) scans and
// store fp32 out coalesced.
// ---------------------------------------------------------------------------
__device__ __forceinline__ bf16x8 lds_frag(const u16* base, int row, int kx, int kseg) {
    const int cp = (kx + kseg * 8) ^ ((row & 7) * 8);
    return *reinterpret_cast<const bf16x8*>(base + row * 64 + cp);
}

#define MFMA_Q(MI0, CNT, NH, BF)                                                     \
    _Pragma("unroll")                                                                \
    for (int kx = 0; kx < 2; ++kx)                                                   \
        _Pragma("unroll")                                                            \
        for (int mi = 0; mi < (CNT); ++mi)                                           \
            _Pragma("unroll")                                                        \
            for (int nj = 0; nj < 2; ++nj)                                           \
                acc[(MI0) + mi][(NH) * 2 + nj] =                                     \
                    __builtin_amdgcn_mfma_f32_16x16x32_bf16(                         \
                        af[mi][kx], BF[nj][kx], acc[(MI0) + mi][(NH) * 2 + nj],      \
                        0, 0, 0);

__global__ __launch_bounds__(512, 2) void gemm_kernel(const u16* __restrict__ xb,
                                                      const u16* __restrict__ bb,
                                                      const float* __restrict__ lam,
                                                      float* __restrict__ out) {
    __shared__ alignas(16) u16 smem[73728];   // 147456B; staging uses 69632 u16
    u16* sA = smem;                   // 2 bufs x 18432 u16 ([288][64])
    u16* sB = smem + 36864;           // 2 bufs x 16384 u16 ([256][64])

    const int tid  = threadIdx.x;
    const int lane = tid & 63;
    const int wid  = tid >> 6;
    const int lrow = lane & 15;
    const int kseg = lane >> 4;
    const int wm   = (wid >> 2) * 144;
    const int wn   = (wid & 3) * 64;

    // T1: XCD-aware mapping (bijective; 256 blocks, 8 XCDs).
    const int bid = blockIdx.x;
    const int xcd = bid & 7, idx = bid >> 3;
    const int bn  = (xcd & 1) * 4 + (idx & 3);
    const int bm  = (xcd >> 1) * 8 + (idx >> 2);

    // staging map: 512 thr * 16B = 64 rows/GLDS; row offsets all 0 mod 8 ->
    // swizzle consistent with reader.
    const int rS = tid >> 3;
    const int cS = ((tid & 7) * 8) ^ ((rS & 7) * 8);
    const u16* gA = xb + (size_t)(bm * 256 + rS) * D_DIM + cS;  // padded space
    const u16* gB = bb + (size_t)(bn * 256 + rS) * D_DIM + cS;

    floatx4 acc[9][4] = {};
    bf16x8 af[5][2], b0[2][2], b1[2][2];

    // ---- prologue: stage A(0), B(0), B(1); keep B(1) in flight
#pragma unroll
    for (int hq = 0; hq < 4; ++hq)
        GLDS(gA + (size_t)(hq * 64) * D_DIM, sA + hq * 4096 + tid * 8);
    if (tid < 256)
        GLDS(gA + (size_t)256 * D_DIM, sA + 16384 + tid * 8);
#pragma unroll
    for (int hq = 0; hq < 4; ++hq)
        GLDS(gB + (size_t)(hq * 64) * D_DIM, sB + hq * 4096 + tid * 8);
#pragma unroll
    for (int hq = 0; hq < 4; ++hq)
        GLDS(gB + (size_t)(hq * 64) * D_DIM + 64, sB + 16384 + hq * 4096 + tid * 8);
    asm volatile("s_waitcnt vmcnt(4)" ::: "memory");
    __builtin_amdgcn_s_barrier();

#pragma unroll 2
    for (int j = 0; j < KT; ++j) {
        const u16* cA  = sA + (j & 1) * 18432;
        const u16* cB  = sB + (j & 1) * 16384;
        u16* dB        = sB + (j & 1) * 16384;        // buf of tile j+2
        const u16* gb2 = gB + (size_t)(j + 2) * 64;   // deref'd only if guarded

        // -------- P1: ds A frags 0..4 + B(nh0); stage A(j+1)
#pragma unroll
        for (int mi = 0; mi < 5; ++mi)
#pragma unroll
            for (int kx = 0; kx < 2; ++kx)
                af[mi][kx] = lds_frag(cA, wm + mi * 16 + lrow, kx * 32, kseg);
#pragma unroll
        for (int nj = 0; nj < 2; ++nj)
#pragma unroll
            for (int kx = 0; kx < 2; ++kx)
                b0[nj][kx] = lds_frag(cB, wn + nj * 16 + lrow, kx * 32, kseg);
        if (j + 1 < KT) {
            u16* dA = sA + ((j + 1) & 1) * 18432;
            const u16* ga = gA + (size_t)(j + 1) * 64;
#pragma unroll
            for (int hq = 0; hq < 4; ++hq)
                GLDS(ga + (size_t)(hq * 64) * D_DIM, dA + hq * 4096 + tid * 8);
            if (tid < 256)
                GLDS(ga + (size_t)256 * D_DIM, dA + 16384 + tid * 8);
        }
        __builtin_amdgcn_s_barrier();
        asm volatile("s_waitcnt lgkmcnt(0)" ::: "memory");
        __builtin_amdgcn_s_setprio(1);
        MFMA_Q(0, 5, 0, b0)
        __builtin_amdgcn_s_setprio(0);
        __builtin_amdgcn_s_barrier();

        // -------- P2: ds B(nh1)
#pragma unroll
        for (int nj = 0; nj < 2; ++nj)
#pragma unroll
            for (int kx = 0; kx < 2; ++kx)
                b1[nj][kx] = lds_frag(cB, wn + 32 + nj * 16 + lrow, kx * 32, kseg);
        __builtin_amdgcn_s_barrier();
        asm volatile("s_waitcnt lgkmcnt(0)" ::: "memory");
        __builtin_amdgcn_s_setprio(1);
        MFMA_Q(0, 5, 1, b1)
        __builtin_amdgcn_s_setprio(0);
        __builtin_amdgcn_s_barrier();

        // -------- P3: ds A frags 5..8; stage B(j+2) half0 (old B reads done @P2)
#pragma unroll
        for (int mi = 0; mi < 4; ++mi)
#pragma unroll
            for (int kx = 0; kx < 2; ++kx)
                af[mi][kx] = lds_frag(cA, wm + 80 + mi * 16 + lrow, kx * 32, kseg);
        if (j + 2 < KT) {
            GLDS(gb2, dB + tid * 8);
            GLDS(gb2 + (size_t)64 * D_DIM, dB + 4096 + tid * 8);
        }
        __builtin_amdgcn_s_barrier();
        asm volatile("s_waitcnt lgkmcnt(0)" ::: "memory");
        __builtin_amdgcn_s_setprio(1);
        MFMA_Q(5, 4, 0, b0)
        __builtin_amdgcn_s_setprio(0);
        __builtin_amdgcn_s_barrier();

        // -------- P4: stage B(j+2) half1; counted vmcnt (after issue!)
        if (j + 2 < KT) {
            GLDS(gb2 + (size_t)128 * D_DIM, dB + 8192 + tid * 8);
            GLDS(gb2 + (size_t)192 * D_DIM, dB + 12288 + tid * 8);
        }
        __builtin_amdgcn_s_barrier();
        asm volatile("s_waitcnt lgkmcnt(0)" ::: "memory");
        __builtin_amdgcn_s_setprio(1);
        MFMA_Q(5, 4, 1, b1)
        __builtin_amdgcn_s_setprio(0);
        if (j < KT - 2) asm volatile("s_waitcnt vmcnt(4)" ::: "memory");
        else            asm volatile("s_waitcnt vmcnt(0)" ::: "memory");
        __builtin_amdgcn_s_barrier();
    }

    // ---- epilogue 1: acc -> LDS u-tile [288][256] bf16, kseg-XOR col swizzle.
    // (row>>2)&3 == kseg since wm=144 and mi*16 are 0 mod 16.
    u16* ut = smem;
#pragma unroll
    for (int mi = 0; mi < 9; ++mi)
#pragma unroll
        for (int nj = 0; nj < 4; ++nj) {
            const int col = wn + nj * 16 + lrow;
#pragma unroll
            for (int r = 0; r < 4; ++r) {
                const int row = wm + mi * 16 + kseg * 4 + r;
                ut[row * 256 + (col ^ (kseg * 16))] = f2bf(acc[mi][nj][r]);
            }
        }
    __syncthreads();

    // ---- epilogue 2: two parallel half-scans per column (32 warm + 128 out).
    {
        const int half = tid >> 8;          // 0 or 1
        const int c    = tid & 255;
        const float a  = 1.0f / (1.0f + __expf(-lam[bn * 256 + c]));
        float h = 0.0f;
        const int rb = half * 128;
#pragma unroll 8
        for (int q = 0; q < 32; ++q) {
            const int l = rb + q;
            h = fmaf(a, h, bf2f(ut[l * 256 + (c ^ (((l >> 2) & 3) * 16))]));
        }
        float* op = out + (size_t)(bm * 256 + rb) * H_DIM + bn * 256 + c;
#pragma unroll 8
        for (int q = 0; q < 128; ++q) {
            const int l = rb + 32 + q;
            h = fmaf(a, h, bf2f(ut[l * 256 + (c ^ (((l >> 2) & 3) * 16))]));
            op[(size_t)q * H_DIM] = h;
        }
    }
}

// ---------------------------------------------------------------------------
extern "C" void kernel_launch(void* const* d_in, const int* in_sizes, int n_in,
                              void* d_out, int out_size, void* d_ws, size_t ws_size,
                              hipStream_t stream) {
    const float* x   = (const float*)d_in[0];   // [T, D]
    const float* lam = (const float*)d_in[1];   // [H]
    const float* B   = (const float*)d_in[2];   // [H, D]
    float* out = (float*)d_out;                 // [T, H]

    // ws: xb [T+32][D] bf16 (16.9MB) + bb [H][D] bf16 (4.2MB) = 21MB.
    u16* xb = (u16*)d_ws;
    u16* bb = xb + (size_t)(T_DIM + PAD_R) * D_DIM;

    const int n4 = ((T_DIM + PAD_R) * D_DIM + H_DIM * D_DIM) / 4;
    conv_kernel<<<(n4 + 255) / 256, 256, 0, stream>>>(x, B, xb, bb);
    gemm_kernel<<<256, 512, 0, stream>>>(xb, bb, lam, out);
}